// Round 5
// baseline (1342.855 us; speedup 1.0000x reference)
//
#include <hip/hip_runtime.h>

typedef unsigned short u16;
typedef __bf16 bf16x8 __attribute__((ext_vector_type(8)));
typedef float f32x4 __attribute__((ext_vector_type(4)));
typedef float f32x4v __attribute__((ext_vector_type(4)));
typedef u16 u16x4 __attribute__((ext_vector_type(4)));

__device__ __forceinline__ float bf2f(u16 u) {
    unsigned x = ((unsigned)u) << 16;
    return __builtin_bit_cast(float, x);
}
__device__ __forceinline__ u16 f2bf(float f) {
    unsigned x = __builtin_bit_cast(unsigned, f);
    unsigned r = (x + 0x7FFFu + ((x >> 16) & 1u)) >> 16;
    return (u16)r;
}

// ---------------- f32 -> bf16 conversion (chunk-strided dest) ----------------
__global__ __launch_bounds__(256) void cvt_kernel(const float* __restrict__ in,
                                                  u16* __restrict__ out, long n,
                                                  long chunk, long stride) {
    for (long i = (long)blockIdx.x * 1024 + (long)threadIdx.x * 4; i < n;
         i += (long)gridDim.x * 1024) {
        f32x4v v = *(const f32x4v*)(in + i);
        u16x4 o;
        o.x = f2bf(v.x); o.y = f2bf(v.y); o.z = f2bf(v.z); o.w = f2bf(v.w);
        long c = i / chunk, rrem = i - c * chunk;
        *(u16x4*)(out + c * stride + rrem) = o;
    }
}

// ---------------- fused qkv bias ----------------
__global__ __launch_bounds__(256) void bias_fuse_kernel(const float* __restrict__ bq,
                                                        const float* __restrict__ bk,
                                                        const float* __restrict__ bv,
                                                        float* __restrict__ dst) {
    int i = blockIdx.x * 256 + threadIdx.x;
    if (i < 6 * 768) {
        int l = i / 768, j = i % 768;
        dst[l * 2304 + j] = bq[i];
        dst[l * 2304 + 768 + j] = bk[i];
        dst[l * 2304 + 1536 + j] = bv[i];
    }
}

// ---------------- embedding ----------------
__global__ __launch_bounds__(256) void embed_kernel(const int* __restrict__ x,
                                                    const float* __restrict__ tok,
                                                    const float* __restrict__ pos,
                                                    float* __restrict__ h) {
    int row = blockIdx.x;           // [0, 2048)
    int t = row & 1023;
    long id = x[row];
    const float* te = tok + id * 768L;
    const float* pe = pos + (long)t * 768L;
    float* o = h + (long)row * 768L;
    for (int d = threadIdx.x; d < 768; d += 256) o[d] = te[d] + pe[d];
}

// ---------------- layernorm (f32 in, bf16 out) ----------------
__global__ __launch_bounds__(256) void ln_kernel(const float* __restrict__ x,
                                                 const float* __restrict__ w,
                                                 const float* __restrict__ b,
                                                 u16* __restrict__ out) {
    __shared__ float red[4];
    int row = blockIdx.x;
    const float* xr = x + (long)row * 768L;
    int tid = threadIdx.x, lane = tid & 63, wid = tid >> 6;
    float v0 = xr[tid], v1 = xr[tid + 256], v2 = xr[tid + 512];
    float s = v0 + v1 + v2;
    for (int o = 32; o; o >>= 1) s += __shfl_xor(s, o);
    if (lane == 0) red[wid] = s;
    __syncthreads();
    float mean = (red[0] + red[1] + red[2] + red[3]) * (1.f / 768.f);
    __syncthreads();
    float d0 = v0 - mean, d1 = v1 - mean, d2 = v2 - mean;
    float q = d0 * d0 + d1 * d1 + d2 * d2;
    for (int o = 32; o; o >>= 1) q += __shfl_xor(q, o);
    if (lane == 0) red[wid] = q;
    __syncthreads();
    float var = (red[0] + red[1] + red[2] + red[3]) * (1.f / 768.f);
    float rstd = rsqrtf(var + 1e-5f);
    u16* orow = out + (long)row * 768L;
    orow[tid]       = f2bf(d0 * rstd * w[tid]       + b[tid]);
    orow[tid + 256] = f2bf(d1 * rstd * w[tid + 256] + b[tid + 256]);
    orow[tid + 512] = f2bf(d2 * rstd * w[tid + 512] + b[tid + 512]);
}

// ---------------- flash attention (causal, DK=64) ----------------
__global__ __launch_bounds__(256) void flash_kernel(
    const u16* __restrict__ qkv,   // [2048][2304]; q col 0, k col 768
    const u16* __restrict__ vT,    // [24][64][1024]
    u16* __restrict__ ctx) {       // [2048][768]
    int z = blockIdx.z;
    int zb = z / 12, zh = z - zb * 12;
    int qt = (int)gridDim.x - 1 - (int)blockIdx.x;  // big tiles first
    int q0 = qt * 64;
    int tid = threadIdx.x, lane = tid & 63, wid = tid >> 6;
    int rA = lane & 15, sA = lane >> 4;

    const u16* Qbase = qkv + (long)zb * 1024 * 2304 + zh * 64;
    const u16* Kbase = Qbase + 768;
    const u16* Vbase = vT + (long)z * 64 * 1024;

    __shared__ u16 Ks[64 * 64];
    __shared__ u16 Vs[64 * 64];
    __shared__ u16 Ps[4][16 * 64];

    bf16x8 aq[2];
    {
        const u16* qrow = Qbase + (long)(q0 + wid * 16 + rA) * 2304;
        aq[0] = *(const bf16x8*)(qrow + sA * 8);
        aq[1] = *(const bf16x8*)(qrow + 32 + sA * 8);
    }

    float m[4], l[4];
    f32x4 acc_o[4];
#pragma unroll
    for (int j = 0; j < 4; j++) { m[j] = -1e30f; l[j] = 0.f; }
#pragma unroll
    for (int nf = 0; nf < 4; nf++) acc_o[nf] = 0.f;

    int grow0 = q0 + wid * 16 + sA * 4;
    int nkv = qt + 1;
    for (int t = 0; t < nkv; ++t) {
        int kv0 = t * 64;
#pragma unroll
        for (int c0 = 0; c0 < 512; c0 += 256) {
            int c = c0 + tid;
            int row = c >> 3, half = (c >> 2) & 1, sl = c & 3;
            int ks = sl ^ ((row >> 1) & 3);
            __builtin_amdgcn_global_load_lds(
                (const __attribute__((address_space(1))) unsigned*)(Kbase + (long)(kv0 + row) * 2304 + half * 32 + ks * 8),
                (__attribute__((address_space(3))) unsigned*)(Ks + c * 8), 16, 0, 0);
        }
#pragma unroll
        for (int c0 = 0; c0 < 512; c0 += 256) {
            int c = c0 + tid;
            int row = c >> 3, half = (c >> 2) & 1, sl = c & 3;
            int ks = sl ^ ((row >> 1) & 3);
            __builtin_amdgcn_global_load_lds(
                (const __attribute__((address_space(1))) unsigned*)(Vbase + (long)row * 1024 + kv0 + half * 32 + ks * 8),
                (__attribute__((address_space(3))) unsigned*)(Vs + c * 8), 16, 0, 0);
        }
        __syncthreads();

        f32x4 s[4];
#pragma unroll
        for (int nf = 0; nf < 4; nf++) s[nf] = 0.f;
#pragma unroll
        for (int h = 0; h < 2; h++)
#pragma unroll
            for (int nf = 0; nf < 4; nf++) {
                int row = nf * 16 + rA;
                bf16x8 bk_ = *(const bf16x8*)(Ks + row * 64 + h * 32 + ((sA ^ ((row >> 1) & 3))) * 8);
                s[nf] = __builtin_amdgcn_mfma_f32_16x16x32_bf16(aq[h], bk_, s[nf], 0, 0, 0);
            }
#pragma unroll
        for (int nf = 0; nf < 4; nf++) {
            int col = kv0 + nf * 16 + rA;
#pragma unroll
            for (int j = 0; j < 4; j++)
                s[nf][j] = (col <= grow0 + j) ? s[nf][j] * 0.125f : -1e30f;
        }
        float pm[4];
#pragma unroll
        for (int j = 0; j < 4; j++) {
            float v = fmaxf(fmaxf(s[0][j], s[1][j]), fmaxf(s[2][j], s[3][j]));
#pragma unroll
            for (int o = 1; o < 16; o <<= 1) v = fmaxf(v, __shfl_xor(v, o));
            pm[j] = v;
        }
        float esc[4];
#pragma unroll
        for (int j = 0; j < 4; j++) {
            float mn = fmaxf(m[j], pm[j]);
            esc[j] = __expf(m[j] - mn);
            m[j] = mn;
        }
        float ts[4] = {0.f, 0.f, 0.f, 0.f};
#pragma unroll
        for (int nf = 0; nf < 4; nf++) {
            int c = nf * 16 + rA;
            int half = c >> 5, ch = (c >> 3) & 3, e = c & 7;
#pragma unroll
            for (int j = 0; j < 4; j++) {
                float p = __expf(s[nf][j] - m[j]);
                ts[j] += p;
                int r = sA * 4 + j;
                Ps[wid][r * 64 + half * 32 + (ch ^ ((r >> 1) & 3)) * 8 + e] = f2bf(p);
            }
        }
#pragma unroll
        for (int j = 0; j < 4; j++) {
            float v = ts[j];
#pragma unroll
            for (int o = 1; o < 16; o <<= 1) v += __shfl_xor(v, o);
            l[j] = l[j] * esc[j] + v;
        }
#pragma unroll
        for (int nf = 0; nf < 4; nf++)
#pragma unroll
            for (int j = 0; j < 4; j++) acc_o[nf][j] *= esc[j];

#pragma unroll
        for (int h = 0; h < 2; h++) {
            bf16x8 ap = *(const bf16x8*)(Ps[wid] + rA * 64 + h * 32 + ((sA ^ ((rA >> 1) & 3))) * 8);
#pragma unroll
            for (int nf = 0; nf < 4; nf++) {
                int row = nf * 16 + rA;
                bf16x8 bv_ = *(const bf16x8*)(Vs + row * 64 + h * 32 + ((sA ^ ((row >> 1) & 3))) * 8);
                acc_o[nf] = __builtin_amdgcn_mfma_f32_16x16x32_bf16(ap, bv_, acc_o[nf], 0, 0, 0);
            }
        }
        __syncthreads();
    }

    float inv[4];
#pragma unroll
    for (int j = 0; j < 4; j++) inv[j] = 1.f / l[j];
    u16* crow = ctx + ((long)zb * 1024 + q0 + wid * 16) * 768 + zh * 64;
#pragma unroll
    for (int nf = 0; nf < 4; nf++)
#pragma unroll
        for (int j = 0; j < 4; j++)
            crow[(long)(sA * 4 + j) * 768 + nf * 16 + rA] = f2bf(acc_o[nf][j] * inv[j]);
}

// ============ 256x256 8-phase GEMM (head: C_f32 = A @ B^T) ============
// 512 thr / 8 waves (2M x 4N); BK=64; LDS 128 KiB (2 dbuf x 2 halves/matrix).
// A-half h: rows with bit6==h of the 256-row tile; B-half h: cols with bit5==h.
// Phase p in 0..7: computes quadrant (mh,nh) = p&3 over tile buf p>>2; stages
// one half-tile (slot freed at p-1); vmcnt(4) only at p3/p7, before barrier.
// Chunk swizzle q ^= (row&7) applied to global source AND ds_read (rule #21).
#define PHASE(BUF, MH, NH, STSTMT, VMSTMT)                                        \
  {                                                                               \
    bf16x8 af[4][2], bfv[2][2];                                                   \
    {                                                                             \
      const u16* Ah = &Al[BUF][MH][0];                                            \
      const u16* Bh = &Bl[BUF][NH][0];                                            \
      _Pragma("unroll") for (int mi = 0; mi < 4; mi++) {                          \
        int rowIdx = (wm << 6) + (mi << 4) + rA;                                  \
        int xo = rowIdx & 7;                                                      \
        _Pragma("unroll") for (int ks = 0; ks < 2; ks++)                          \
          af[mi][ks] = *(const bf16x8*)(Ah + rowIdx * 64 + (((ks << 2) + sA) ^ xo) * 8); \
      }                                                                           \
      _Pragma("unroll") for (int ni = 0; ni < 2; ni++) {                          \
        int colIdx = (wn << 5) + (ni << 4) + rA;                                  \
        int xo = colIdx & 7;                                                      \
        _Pragma("unroll") for (int ks = 0; ks < 2; ks++)                          \
          bfv[ni][ks] = *(const bf16x8*)(Bh + colIdx * 64 + (((ks << 2) + sA) ^ xo) * 8); \
      }                                                                           \
    }                                                                             \
    STSTMT;                                                                       \
    VMSTMT;                                                                       \
    __builtin_amdgcn_s_barrier();                                                 \
    __builtin_amdgcn_s_setprio(1);                                                \
    _Pragma("unroll") for (int mi = 0; mi < 4; mi++)                              \
      _Pragma("unroll") for (int ni = 0; ni < 2; ni++)                            \
        _Pragma("unroll") for (int ks = 0; ks < 2; ks++)                          \
          acc[(MH << 2) + mi][(NH << 1) + ni] =                                   \
              __builtin_amdgcn_mfma_f32_16x16x32_bf16(                            \
                  af[mi][ks], bfv[ni][ks], acc[(MH << 2) + mi][(NH << 1) + ni], 0, 0, 0); \
    __builtin_amdgcn_s_setprio(0);                                                \
    __builtin_amdgcn_s_barrier();                                                 \
  }

__global__ __launch_bounds__(512) void gemm256_kernel(
    const u16* __restrict__ A, const u16* __restrict__ Bm,
    float* __restrict__ C, int Ndim, int K, int gm) {
    __shared__ u16 Al[2][2][128 * 64];
    __shared__ u16 Bl[2][2][128 * 64];

    int nwg = gridDim.x, flat = blockIdx.x;
    int qq = nwg >> 3, rr = nwg & 7;
    int xcd = flat & 7, wi = flat >> 3;
    int swz = (xcd < rr) ? (xcd * (qq + 1) + wi) : (rr * (qq + 1) + (xcd - rr) * qq + wi);
    int ntile = swz / gm, mt = swz - ntile * gm;
    int bm0 = mt * 256, bn0 = ntile * 256;

    int tid = threadIdx.x, lane = tid & 63, wid = tid >> 6;
    int wm = wid >> 2, wn = wid & 3;
    int rA = lane & 15, sA = lane >> 4;

    // stage one half-tile (2 x global_load_lds / thread)
    auto stageA = [&](int b, int h, int t) {
#pragma unroll
        for (int j = 0; j < 2; j++) {
            int c = tid + j * 512;
            int r = c >> 3, q = c & 7;
            int grow = bm0 + ((r >> 6) << 7) + (h << 6) + (r & 63);
            int gk = (t << 6) + ((q ^ (r & 7)) << 3);
            __builtin_amdgcn_global_load_lds(
                (const __attribute__((address_space(1))) unsigned*)(A + (long)grow * K + gk),
                (__attribute__((address_space(3))) unsigned*)(&Al[b][h][c * 8]), 16, 0, 0);
        }
    };
    auto stageB = [&](int b, int h, int t) {
#pragma unroll
        for (int j = 0; j < 2; j++) {
            int c = tid + j * 512;
            int r = c >> 3, q = c & 7;
            int gn = bn0 + ((r >> 5) << 6) + (h << 5) + (r & 31);
            int gk = (t << 6) + ((q ^ (r & 7)) << 3);
            __builtin_amdgcn_global_load_lds(
                (const __attribute__((address_space(1))) unsigned*)(Bm + (long)gn * K + gk),
                (__attribute__((address_space(3))) unsigned*)(&Bl[b][h][c * 8]), 16, 0, 0);
        }
    };

    f32x4 acc[8][4];
#pragma unroll
    for (int i = 0; i < 8; i++)
#pragma unroll
        for (int j = 0; j < 4; j++) acc[i][j] = 0.f;

    const int NT = K >> 6, NITER = NT >> 1;

    // prologue: tile0 fully + tile1 halves 0 (12 loads; drain first 8)
    stageA(0, 0, 0); stageB(0, 0, 0); stageA(0, 1, 0); stageB(0, 1, 0);
    stageA(1, 0, 1); stageB(1, 0, 1);
    asm volatile("s_waitcnt vmcnt(4)" ::: "memory");
    __builtin_amdgcn_sched_barrier(0);
    __builtin_amdgcn_s_barrier();

    for (int i = 0; i < NITER; ++i) {
        int t2 = 2 * i + 2, t3 = 2 * i + 3;
        bool p2ok = t2 < NT, p3ok = t3 < NT;
        // p0: tile 2i q(0,0); stage A1(2i+1)->buf1
        PHASE(0, 0, 0, { stageA(1, 1, 2 * i + 1); }, {});
        // p1: q(0,1); stage B1(2i+1)->buf1
        PHASE(0, 0, 1, { stageB(1, 1, 2 * i + 1); }, {});
        // p2: q(1,0); stage A0(2i+2)->buf0
        PHASE(0, 1, 0, { if (p2ok) stageA(0, 0, t2); }, {});
        // p3: q(1,1); stage B0(2i+2)->buf0 ; vmcnt
        PHASE(0, 1, 1, { if (p2ok) stageB(0, 0, t2); }, {
            if (i == NITER - 1) { asm volatile("s_waitcnt vmcnt(0)" ::: "memory"); }
            else { asm volatile("s_waitcnt vmcnt(4)" ::: "memory"); }
            __builtin_amdgcn_sched_barrier(0);
        });
        // p4: tile 2i+1 q(0,0); stage A1(2i+2)->buf0
        PHASE(1, 0, 0, { if (p2ok) stageA(0, 1, t2); }, {});
        // p5: q(0,1); stage B1(2i+2)->buf0
        PHASE(1, 0, 1, { if (p2ok) stageB(0, 1, t2); }, {});
        // p6: q(1,0); stage A0(2i+3)->buf1
        PHASE(1, 1, 0, { if (p3ok) stageA(1, 0, t3); }, {});
        // p7: q(1,1); stage B0(2i+3)->buf1 ; vmcnt
        PHASE(1, 1, 1, { if (p3ok) stageB(1, 0, t3); }, {
            asm volatile("s_waitcnt vmcnt(4)" ::: "memory");
            __builtin_amdgcn_sched_barrier(0);
        });
    }

    // epilogue: f32 C write
#pragma unroll
    for (int mi8 = 0; mi8 < 8; mi8++) {
        int grow = bm0 + (wm << 7) + ((mi8 >> 2) << 6) + ((mi8 & 3) << 4) + (sA << 2);
#pragma unroll
        for (int ni4 = 0; ni4 < 4; ni4++) {
            int gcol = bn0 + (wn << 6) + (ni4 << 4) + rA;
#pragma unroll
            for (int j = 0; j < 4; j++)
                C[(long)(grow + j) * Ndim + gcol] = acc[mi8][ni4][j];
        }
    }
}

// ---------------- MFMA GEMM v3: double-buffered 2-phase + swizzled LDS ----
template <int BM, int BN, int EPI, bool CSKIP, bool KLIM>
__global__ __launch_bounds__(256) void gemm3_kernel(
    const u16* __restrict__ A, int lda, long sAb, long sAh,
    const u16* __restrict__ Bm, int ldb, long sBb, long sBh,
    void* __restrict__ Cv, int ldc, long sCb, long sCh,
    const float* __restrict__ bias, int K, int gm, int Hh, float scale,
    u16* __restrict__ aux) {
    constexpr int BK = 32;
    int nwg = gridDim.x, flat = blockIdx.x;
    int qq = nwg >> 3, rr = nwg & 7;
    int xcd = flat & 7, wi = flat >> 3;
    int swz = (xcd < rr) ? (xcd * (qq + 1) + wi) : (rr * (qq + 1) + (xcd - rr) * qq + wi);
    int ntile = swz / gm, mt = swz - ntile * gm;
    int bm0 = mt * BM, bn0 = ntile * BN;
    if (CSKIP && bn0 > bm0 + BM - 1) return;
    int z = blockIdx.z;
    int zb = z / Hh, zh = z - zb * Hh;
    const u16* Ab = A + zb * sAb + zh * sAh + (long)bm0 * lda;
    const u16* Bb = Bm + zb * sBb + zh * sBh + (long)bn0 * ldb;

    __shared__ u16 As[2][BM * BK];
    __shared__ u16 Bs[2][BN * BK];

    int tid = threadIdx.x, lane = tid & 63, wid = tid >> 6;
    constexpr int WM = BM / 2, WN = BN / 2, MR = WM / 16, NR = WN / 16;
    int wm0 = (wid >> 1) * WM, wn0 = (wid & 1) * WN;

    f32x4 acc[MR][NR];
#pragma unroll
    for (int mi = 0; mi < MR; mi++)
#pragma unroll
        for (int ni = 0; ni < NR; ni++) acc[mi][ni] = 0.f;

    int Keff = KLIM ? (bm0 + BM < K ? bm0 + BM : K) : K;
    int nt = Keff / BK;

    auto stage = [&](int buf, int k0) {
        constexpr int CA = BM * 4;
#pragma unroll
        for (int c0 = 0; c0 < CA; c0 += 256) {
            int c = c0 + tid;
            int row = c >> 2, sl = c & 3;
            int ks = sl ^ ((row >> 1) & 3);
            __builtin_amdgcn_global_load_lds(
                (const __attribute__((address_space(1))) unsigned*)(Ab + (long)row * lda + k0 + ks * 8),
                (__attribute__((address_space(3))) unsigned*)(As[buf] + c * 8), 16, 0, 0);
        }
        constexpr int CB = BN * 4;
#pragma unroll
        for (int c0 = 0; c0 < CB; c0 += 256) {
            int c = c0 + tid;
            int row = c >> 2, sl = c & 3;
            int ks = sl ^ ((row >> 1) & 3);
            __builtin_amdgcn_global_load_lds(
                (const __attribute__((address_space(1))) unsigned*)(Bb + (long)row * ldb + k0 + ks * 8),
                (__attribute__((address_space(3))) unsigned*)(Bs[buf] + c * 8), 16, 0, 0);
        }
    };

    stage(0, 0);
    __syncthreads();
    int cur = 0;
    int rA = lane & 15, sA = lane >> 4;
    int sswz = (sA ^ ((rA >> 1) & 3)) * 8;
    for (int t = 0; t < nt; ++t) {
        if (t + 1 < nt) stage(cur ^ 1, (t + 1) * BK);
        bf16x8 af[MR], bfr[NR];
#pragma unroll
        for (int mi = 0; mi < MR; mi++)
            af[mi] = *(const bf16x8*)(As[cur] + (wm0 + mi * 16 + rA) * BK + sswz);
#pragma unroll
        for (int ni = 0; ni < NR; ni++)
            bfr[ni] = *(const bf16x8*)(Bs[cur] + (wn0 + ni * 16 + rA) * BK + sswz);
#pragma unroll
        for (int mi = 0; mi < MR; mi++)
#pragma unroll
            for (int ni = 0; ni < NR; ni++)
                acc[mi][ni] = __builtin_amdgcn_mfma_f32_16x16x32_bf16(
                    af[mi], bfr[ni], acc[mi][ni], 0, 0, 0);
        __syncthreads();
        cur ^= 1;
    }

    long coff = zb * sCb + zh * sCh;
#pragma unroll
    for (int mi = 0; mi < MR; mi++)
#pragma unroll
        for (int ni = 0; ni < NR; ni++) {
            int gmb = bm0 + wm0 + mi * 16 + ((lane >> 4) << 2);
            int gn = bn0 + wn0 + ni * 16 + (lane & 15);
            if (EPI == 6) {
                if (gn < 1536) {
#pragma unroll
                    for (int j = 0; j < 4; j++)
                        ((u16*)Cv)[(long)(gmb + j) * ldc + gn] =
                            f2bf(acc[mi][ni][j] + bias[gn]);
                } else {
                    u16x4 o;
#pragma unroll
                    for (int j = 0; j < 4; j++) o[j] = f2bf(acc[mi][ni][j] + bias[gn]);
                    int hh = (gn - 1536) >> 6, dk = gn & 63;
                    long off = ((long)((gmb >> 10) * 12 + hh) * 64 + dk) * 1024 + (gmb & 1023);
                    *(u16x4*)(aux + off) = o;
                }
            } else {
#pragma unroll
                for (int j = 0; j < 4; j++) {
                    float v = acc[mi][ni][j];
                    long idx = coff + (long)(gmb + j) * ldc + gn;
                    if (EPI == 1) ((u16*)Cv)[idx] = f2bf(v + bias[gn]);
                    else if (EPI == 2) ((u16*)Cv)[idx] = f2bf(fmaxf(v + bias[gn], 0.f));
                    else if (EPI == 3) { float* C = (float*)Cv; C[idx] = C[idx] + v + bias[gn]; }
                    else if (EPI == 5) ((float*)Cv)[idx] = v;
                    else ((u16*)Cv)[idx] = f2bf(v * scale);
                }
            }
        }
}

// ---------------- host side ----------------
extern "C" void kernel_launch(void* const* d_in, const int* in_sizes, int n_in,
                              void* d_out, int out_size, void* d_ws, size_t ws_size,
                              hipStream_t stream) {
    const int L = 6, D = 768, Hn = 12, F = 3072, T = 1024, V = 32000;
    const int M = 2048;  // B*T
    const int* x = (const int*)d_in[0];
    const float* tok = (const float*)d_in[1];
    const float* pos = (const float*)d_in[2];
    const float* ln1w = (const float*)d_in[3];
    const float* ln1b = (const float*)d_in[4];
    const float* wq = (const float*)d_in[5];
    const float* bq = (const float*)d_in[6];
    const float* wk = (const float*)d_in[7];
    const float* bk = (const float*)d_in[8];
    const float* wv = (const float*)d_in[9];
    const float* bv = (const float*)d_in[10];
    const float* wo = (const float*)d_in[11];
    const float* bo = (const float*)d_in[12];
    const float* ln2w = (const float*)d_in[13];
    const float* ln2b = (const float*)d_in[14];
    const float* w1 = (const float*)d_in[15];
    const float* b1 = (const float*)d_in[16];
    const float* w2 = (const float*)d_in[17];
    const float* b2 = (const float*)d_in[18];
    const float* lnfw = (const float*)d_in[19];
    const float* lnfb = (const float*)d_in[20];
    const float* headw = (const float*)d_in[21];

    char* p = (char*)d_ws;
    auto alloc = [&](size_t bytes) {
        char* r = p;
        p += (bytes + 255) & ~(size_t)255;
        return r;
    };
    const long DD = (long)D * D, FD = (long)F * D;
    u16* qkvw_b = (u16*)alloc(L * 3 * DD * 2);   // [L][2304][768] fused
    u16* wo_b = (u16*)alloc(L * DD * 2);
    u16* w1_b = (u16*)alloc(L * FD * 2);
    u16* w2_b = (u16*)alloc(L * FD * 2);
    u16* hw_b = (u16*)alloc((long)V * D * 2);
    float* qkvbias = (float*)alloc(L * 2304 * 4);
    float* h = (float*)alloc((long)M * D * 4);
    u16* a = (u16*)alloc((long)M * D * 2);
    u16* qkvb = (u16*)alloc((long)M * 2304 * 2);
    u16* vT = (u16*)alloc(24L * 64 * T * 2);     // [B*H][64][T]
    u16* ctxb = (u16*)alloc((long)M * D * 2);
    u16* f1 = (u16*)alloc((long)M * F * 2);

    auto cvt = [&](const float* src, u16* dst, long n, long chunk, long stride) {
        long blocks = (n + 1023) / 1024;
        if (blocks > 8192) blocks = 8192;
        cvt_kernel<<<dim3((unsigned)blocks), 256, 0, stream>>>(src, dst, n, chunk, stride);
    };
    cvt(wq, qkvw_b, L * DD, DD, 3 * DD);
    cvt(wk, qkvw_b + DD, L * DD, DD, 3 * DD);
    cvt(wv, qkvw_b + 2 * DD, L * DD, DD, 3 * DD);
    cvt(wo, wo_b, L * DD, L * DD, L * DD);
    cvt(w1, w1_b, L * FD, L * FD, L * FD);
    cvt(w2, w2_b, L * FD, L * FD, L * FD);
    cvt(headw, hw_b, (long)V * D, (long)V * D, (long)V * D);
    bias_fuse_kernel<<<dim3(18), 256, 0, stream>>>(bq, bk, bv, qkvbias);

    embed_kernel<<<dim3(M), 256, 0, stream>>>(x, tok, pos, h);

    for (int i = 0; i < L; i++) {
        ln_kernel<<<dim3(M), 256, 0, stream>>>(h, ln1w + i * D, ln1b + i * D, a);
        gemm3_kernel<128, 128, 6, false, false><<<dim3(16 * 18, 1, 1), 256, 0, stream>>>(
            a, D, 0, 0, qkvw_b + i * 3 * DD, D, 0, 0, qkvb, 2304, 0, 0,
            qkvbias + i * 2304, D, 16, 1, 0.f, vT);
        flash_kernel<<<dim3(16, 1, 24), 256, 0, stream>>>(qkvb, vT, ctxb);
        gemm3_kernel<64, 128, 3, false, false><<<dim3(32 * 6, 1, 1), 256, 0, stream>>>(
            ctxb, D, 0, 0, wo_b + i * DD, D, 0, 0, h, D, 0, 0,
            bo + i * D, D, 32, 1, 0.f, nullptr);
        ln_kernel<<<dim3(M), 256, 0, stream>>>(h, ln2w + i * D, ln2b + i * D, a);
        gemm3_kernel<128, 128, 2, false, false><<<dim3(16 * 24, 1, 1), 256, 0, stream>>>(
            a, D, 0, 0, w1_b + i * FD, D, 0, 0, f1, F, 0, 0,
            b1 + i * F, D, 16, 1, 0.f, nullptr);
        gemm3_kernel<64, 128, 3, false, false><<<dim3(32 * 6, 1, 1), 256, 0, stream>>>(
            f1, F, 0, 0, w2_b + i * FD, F, 0, 0, h, D, 0, 0,
            b2 + i * D, F, 32, 1, 0.f, nullptr);
    }
    ln_kernel<<<dim3(M), 256, 0, stream>>>(h, lnfw, lnfb, a);
    // logits = a @ head_w^T -> f32 d_out  (256^2 8-phase kernel)
    gemm256_kernel<<<dim3((M / 256) * (V / 256)), 512, 0, stream>>>(
        a, hw_b, (float*)d_out, V, D, M / 256);
}